// Round 1
// baseline (175.397 us; speedup 1.0000x reference)
//
#include <hip/hip_runtime.h>

// Problem constants:
// inputs: (B=8, C=2, D=96, H=64, W=64) f32
// weight/bias: (F=8, C=2, d=3, h=60, w=64) f32
// out: (B=8, F=8, Dout=94, h=60, w=64) f32
#define B_ 8
#define C_ 2
#define D_ 96
#define H_ 64
#define W_ 64
#define F_ 8
#define KD 3
#define h_ 60
#define Dout_ 94
#define PLANE (h_ * W_)          // 3840 floats
#define NCH (PLANE / 4)          // 960 float4 chunks
#define TD 4                     // douts per block in k_main
#define NTILE ((Dout_ + TD - 1) / TD)  // 24
#define NS2 (B_ * C_ * D_)       // 1536 s2 planes
#define S2_FLOATS ((size_t)NS2 * PLANE)
#define ST 17                    // LDS row stride (float4) — padded vs 16 to rotate banks

typedef float fv4 __attribute__((ext_vector_type(4)));

// Horizontal 3-tap sum via lane shuffles; col4 = position 0..15 within a
// 16-lane row group. Boundary cols contribute zero. (Used by k_prep only.)
__device__ __forceinline__ float4 hsum3(float4 V, int col4) {
    const int lane = threadIdx.x & 63;
    float lw = __shfl(V.w, (lane + 63) & 63, 64);
    float rx = __shfl(V.x, (lane + 1) & 63, 64);
    if (col4 == 0) lw = 0.f;
    if (col4 == 15) rx = 0.f;
    float4 o;
    o.x = lw + V.x + V.y;
    o.y = V.x + V.y + V.z;
    o.z = V.y + V.z + V.w;
    o.w = V.z + V.w + rx;
    return o;
}

// ---------------------------------------------------------------------------
// Fused prep kernel (unchanged).
// Blocks 0..NS2-1:            S2[b,c,p] = vertical 5-sum of input plane.
// Blocks NS2..NS2+F_-1:       BoxBS[f]  = Box3x3( sum_{c,z} bias[f,c,z] ).
// ---------------------------------------------------------------------------
__global__ __launch_bounds__(256) void k_prep(const float* __restrict__ in,
                                              const float* __restrict__ bs,
                                              float* __restrict__ s2,
                                              float* __restrict__ bb) {
    const int bx = blockIdx.x;
    const int tid = threadIdx.x;
    __shared__ float4 lds[H_ * 16];  // 16 KB (>= 62*16 used by bias path)

    if (bx < NS2) {
        const float4* ip4 = (const float4*)(in + (size_t)bx * (H_ * W_));
        float4* op4 = (float4*)(s2 + (size_t)bx * PLANE);
#pragma unroll
        for (int k = 0; k < 4; ++k) lds[tid + 256 * k] = ip4[tid + 256 * k];
        __syncthreads();
#pragma unroll
        for (int k = 0; k < 4; ++k) {
            const int e = tid + 256 * k;
            if (e < NCH) {
                const int row = e >> 4, col = e & 15;
                float4 s = lds[row * 16 + col];
#pragma unroll
                for (int j = 1; j < 5; ++j) {
                    const float4 v = lds[(row + j) * 16 + col];
                    s.x += v.x; s.y += v.y; s.z += v.z; s.w += v.w;
                }
                op4[e] = s;
            }
        }
    } else {
        const int f = bx - NS2;
        float4* R = lds;  // rows 0..61, row 0 and 61 zero
        if (tid < 32) {
            const int r = (tid >> 4) ? 61 : 0;
            R[r * 16 + (tid & 15)] = make_float4(0, 0, 0, 0);
        }
        const float4* bp = (const float4*)(bs + (size_t)f * (C_ * KD * PLANE));
#pragma unroll
        for (int k = 0; k < 4; ++k) {
            const int e = tid + 256 * k;
            if (e < NCH) {
                float4 s = make_float4(0, 0, 0, 0);
#pragma unroll
                for (int s6 = 0; s6 < 6; ++s6) {
                    const float4 v = bp[s6 * NCH + e];
                    s.x += v.x; s.y += v.y; s.z += v.z; s.w += v.w;
                }
                R[((e >> 4) + 1) * 16 + (e & 15)] = s;
            }
        }
        __syncthreads();
        float4* ob = (float4*)(bb + (size_t)f * PLANE);
#pragma unroll
        for (int k = 0; k < 4; ++k) {
            const int e = tid + 256 * k;
            if (e < NCH) {
                const int row = e >> 4, c4 = e & 15;
                const float4 a = R[row * 16 + c4];
                const float4 m = R[(row + 1) * 16 + c4];
                const float4 d = R[(row + 2) * 16 + c4];
                float4 V;
                V.x = a.x + m.x + d.x; V.y = a.y + m.y + d.y;
                V.z = a.z + m.z + d.z; V.w = a.w + m.w + d.w;
                ob[e] = hsum3(V, c4);
            }
        }
    }
}

// ---------------------------------------------------------------------------
// Main kernel, restructured for occupancy (R1):
//  * 512 threads; thread = (row r = t>>3, col-pair p8 = t&7): 2 adjacent float4
//    of one row. Weight reg cache halves: 12 float4/thread (was 24) -> target
//    <=128 unified VGPR+AGPR -> 4 waves/SIMD (2 blocks/CU, 16 waves) vs ~3.
//  * XCD pinning: b = blockIdx.x & 7 (B_ == 8 XCDs). All blocks of one b land
//    on one XCD -> its 2.9 MB S2 slice resides in that XCD's 4 MB L2.
//  * Vertical box reuses own acc as the middle row: LDS read 4 float4 (was 12);
//    horizontal box needs only 2 shuffles per thread (was 4).
//  * LDS row stride padded to 17 float4 (bank rotation); double-buffered,
//    ONE barrier per dout.
//  * Nontemporal output stores: don't let the 92 MB write stream evict S2/L2.
// ---------------------------------------------------------------------------
__global__ __launch_bounds__(512, 4) void k_main(const float* __restrict__ s2,
                                                 const float* __restrict__ wt,
                                                 const float* __restrict__ bb,
                                                 float* __restrict__ out) {
    const int bx = blockIdx.x;
    const int b = bx & 7;            // XCD-pinned batch index
    const int f = (bx >> 3) & 7;
    const int tile = bx >> 6;        // 0..23
    const int d0 = tile * TD;
    const int t = threadIdx.x;
    const int p8 = t & 7;            // col-pair 0..7
    const int r = t >> 3;            // row 0..63 (rows 0..59 active)
    const int c0 = 2 * p8;           // float4 col 0..15 (even)
    const int e0 = r * 16 + c0;      // plane chunk index of first float4
    const bool act = (r < h_);
    const int lane = t & 63;

    __shared__ float4 R[2][62 * ST]; // 2 x 16864 B = 33728 B

    // zero the pad rows (0 and 61) of both buffers
    if (t < 64) {
        const int buf = t >> 5;
        const int idx = t & 31;
        const int row = (idx >> 4) ? 61 : 0;
        R[buf][row * ST + (idx & 15)] = make_float4(0, 0, 0, 0);
    }

    // per-thread weight cache: 12 float4 = 48 regs (was 24/96)
    float4 wreg[6][2];
    float4 bb0 = make_float4(0, 0, 0, 0), bb1 = make_float4(0, 0, 0, 0);
    const float4* wp = (const float4*)(wt + (size_t)f * (C_ * KD * PLANE));
    const float4* bbp = (const float4*)(bb + (size_t)f * PLANE);
    if (act) {
#pragma unroll
        for (int s6 = 0; s6 < 6; ++s6) {
            wreg[s6][0] = wp[s6 * NCH + e0];
            wreg[s6][1] = wp[s6 * NCH + e0 + 1];
        }
        bb0 = bbp[e0];
        bb1 = bbp[e0 + 1];
    }

    const float4* s2b = (const float4*)s2 + (size_t)(b * C_) * D_ * NCH;
    float* ob = out + (size_t)((b * F_ + f) * Dout_) * PLANE;

#pragma unroll
    for (int td = 0; td < TD; ++td) {
        const int dout = d0 + td;

        float4 a0 = make_float4(0, 0, 0, 0);
        float4 a1 = make_float4(0, 0, 0, 0);
        if (act) {
#pragma unroll
            for (int c = 0; c < C_; ++c)
#pragma unroll
                for (int z = 0; z < KD; ++z) {
                    int pp = dout + z; if (pp > D_ - 1) pp = D_ - 1;  // tail clamp
                    const float4* sp = s2b + (size_t)(c * D_ + pp) * NCH;
                    const float4 v0 = sp[e0];
                    const float4 v1 = sp[e0 + 1];
                    const float4 w0 = wreg[c * KD + z][0];
                    const float4 w1 = wreg[c * KD + z][1];
                    a0.x += v0.x * w0.x; a0.y += v0.y * w0.y;
                    a0.z += v0.z * w0.z; a0.w += v0.w * w0.w;
                    a1.x += v1.x * w1.x; a1.y += v1.y * w1.y;
                    a1.z += v1.z * w1.z; a1.w += v1.w * w1.w;
                }
        }

        float4* Rb = R[td & 1];
        if (act) {
            Rb[(r + 1) * ST + c0]     = a0;
            Rb[(r + 1) * ST + c0 + 1] = a1;
        }
        __syncthreads();   // single barrier per dout (dbuf prevents WAR)

        if (act && dout < Dout_) {
            // vertical 3-tap: rows r-1 (LDS), r (own acc), r+1 (LDS)
            const float4 u0 = Rb[r * ST + c0];
            const float4 u1 = Rb[r * ST + c0 + 1];
            const float4 dn0 = Rb[(r + 2) * ST + c0];
            const float4 dn1 = Rb[(r + 2) * ST + c0 + 1];
            float4 V0, V1;
            V0.x = u0.x + a0.x + dn0.x; V0.y = u0.y + a0.y + dn0.y;
            V0.z = u0.z + a0.z + dn0.z; V0.w = u0.w + a0.w + dn0.w;
            V1.x = u1.x + a1.x + dn1.x; V1.y = u1.y + a1.y + dn1.y;
            V1.z = u1.z + a1.z + dn1.z; V1.w = u1.w + a1.w + dn1.w;

            // horizontal 3-tap: only 2 cross-lane words needed
            float lw = __shfl(V1.w, (lane + 63) & 63, 64);
            float rx = __shfl(V0.x, (lane + 1) & 63, 64);
            if (p8 == 0) lw = 0.f;   // col 0 boundary
            if (p8 == 7) rx = 0.f;   // col 63 boundary
            float4 o0, o1;
            o0.x = lw   + V0.x + V0.y;
            o0.y = V0.x + V0.y + V0.z;
            o0.z = V0.y + V0.z + V0.w;
            o0.w = V0.z + V0.w + V1.x;
            o1.x = V0.w + V1.x + V1.y;
            o1.y = V1.x + V1.y + V1.z;
            o1.z = V1.y + V1.z + V1.w;
            o1.w = V1.z + V1.w + rx;

            o0.x = 0.25f * (o0.x + bb0.x); o0.y = 0.25f * (o0.y + bb0.y);
            o0.z = 0.25f * (o0.z + bb0.z); o0.w = 0.25f * (o0.w + bb0.w);
            o1.x = 0.25f * (o1.x + bb1.x); o1.y = 0.25f * (o1.y + bb1.y);
            o1.z = 0.25f * (o1.z + bb1.z); o1.w = 0.25f * (o1.w + bb1.w);
            o0.x = (o0.x > 0.f) ? o0.x : 0.2f * o0.x;
            o0.y = (o0.y > 0.f) ? o0.y : 0.2f * o0.y;
            o0.z = (o0.z > 0.f) ? o0.z : 0.2f * o0.z;
            o0.w = (o0.w > 0.f) ? o0.w : 0.2f * o0.w;
            o1.x = (o1.x > 0.f) ? o1.x : 0.2f * o1.x;
            o1.y = (o1.y > 0.f) ? o1.y : 0.2f * o1.y;
            o1.z = (o1.z > 0.f) ? o1.z : 0.2f * o1.z;
            o1.w = (o1.w > 0.f) ? o1.w : 0.2f * o1.w;

            float4* od4 = (float4*)(ob + (size_t)dout * PLANE);
            __builtin_nontemporal_store(*(const fv4*)&o0, (fv4*)(od4 + e0));
            __builtin_nontemporal_store(*(const fv4*)&o1, (fv4*)(od4 + e0 + 1));
        }
    }
}

extern "C" void kernel_launch(void* const* d_in, const int* in_sizes, int n_in,
                              void* d_out, int out_size, void* d_ws, size_t ws_size,
                              hipStream_t stream) {
    const float* in = (const float*)d_in[0];
    const float* wt = (const float*)d_in[1];
    const float* bs = (const float*)d_in[2];
    float* out = (float*)d_out;

    float* s2 = (float*)d_ws;
    float* bb = s2 + S2_FLOATS;

    k_prep<<<dim3(NS2 + F_), dim3(256), 0, stream>>>(in, bs, s2, bb);
    k_main<<<dim3(B_ * F_ * NTILE), dim3(512), 0, stream>>>(s2, wt, bb, out);
}